// Round 1
// baseline (130.723 us; speedup 1.0000x reference)
//
#include <hip/hip_runtime.h>

// NSLayer: per 8x8 matrix x (262144 of them):
//   A = I - x x^T  (symmetric)
//   out = x + (w0 A + w1 A^2 + ... + w6 A^7 + w7 I) @ x
// Horner on the vector: z6 = w6 x; z_{k} = w_k x + A z_{k+1} (k=5..0);
//   out = (1 + w7) x + A z0.
// Decomposition: 2 lanes per matrix; lane h in {0,1} owns global rows h*4..h*4+3.
// A is stored with lane-permuted columns: A[i][c] with c<4 -> global col h*4+c,
// c>=4 -> global col (1-h)*4+(c-4). All register indices compile-time constant.

__global__ __launch_bounds__(256, 2)
void ns_poly_kernel(const float* __restrict__ in,
                    const float* __restrict__ wp,
                    float* __restrict__ out)
{
    const int tid = threadIdx.x;
    const int m   = blockIdx.x * 128 + (tid >> 1);   // matrix index
    const int h   = tid & 1;                         // row-half

    const float* xm = in  + (size_t)m * 64 + (size_t)h * 32;
    float*       om = out + (size_t)m * 64 + (size_t)h * 32;

    // weights (uniform address -> scalarized by compiler)
    const float w0 = wp[0], w1 = wp[1], w2 = wp[2], w3 = wp[3];
    const float w4 = wp[4], w5 = wp[5], w6 = wp[6], w7 = wp[7];

    // load our 4 rows (16B vector loads)
    float x[4][8];
#pragma unroll
    for (int r = 0; r < 4; ++r) {
        const float4 a = reinterpret_cast<const float4*>(xm)[2 * r];
        const float4 b = reinterpret_cast<const float4*>(xm)[2 * r + 1];
        x[r][0] = a.x; x[r][1] = a.y; x[r][2] = a.z; x[r][3] = a.w;
        x[r][4] = b.x; x[r][5] = b.y; x[r][6] = b.z; x[r][7] = b.w;
    }

    // partner's 4 rows (global rows (1-h)*4 .. (1-h)*4+3)
    float xo[4][8];
#pragma unroll
    for (int r = 0; r < 4; ++r)
#pragma unroll
        for (int j = 0; j < 8; ++j)
            xo[r][j] = __shfl_xor(x[r][j], 1);

    // A = I - x x^T, lane-permuted columns. Local 4x4 block is symmetric.
    float A[4][8];
#pragma unroll
    for (int i = 0; i < 4; ++i) {
#pragma unroll
        for (int c = 0; c < 4; ++c) {
            if (c < i) continue;                     // filled by symmetry
            float s = x[i][0] * x[c][0];
#pragma unroll
            for (int k = 1; k < 8; ++k) s += x[i][k] * x[c][k];
            const float v = (i == c ? 1.0f : 0.0f) - s;
            A[i][c] = v;
            A[c][i] = v;
        }
#pragma unroll
        for (int r = 0; r < 4; ++r) {               // cross-half block (delta = 0)
            float s = x[i][0] * xo[r][0];
#pragma unroll
            for (int k = 1; k < 8; ++k) s += x[i][k] * xo[r][k];
            A[i][4 + r] = -s;
        }
    }

    // Horner state: t = w6 * x
    float t[4][8];
#pragma unroll
    for (int i = 0; i < 4; ++i)
#pragma unroll
        for (int j = 0; j < 8; ++j)
            t[i][j] = w6 * x[i][j];

    // one step: t <- wk*x + A*t
    auto horner_step = [&](float wk) {
        float to[4][8];
#pragma unroll
        for (int r = 0; r < 4; ++r)
#pragma unroll
            for (int j = 0; j < 8; ++j)
                to[r][j] = __shfl_xor(t[r][j], 1);   // partner's t rows
        float tn[4][8];
#pragma unroll
        for (int i = 0; i < 4; ++i)
#pragma unroll
            for (int j = 0; j < 8; ++j) {
                float s = wk * x[i][j];
#pragma unroll
                for (int r = 0; r < 4; ++r) s += A[i][r]     * t[r][j];
#pragma unroll
                for (int r = 0; r < 4; ++r) s += A[i][4 + r] * to[r][j];
                tn[i][j] = s;
            }
#pragma unroll
        for (int i = 0; i < 4; ++i)
#pragma unroll
            for (int j = 0; j < 8; ++j)
                t[i][j] = tn[i][j];
    };

    horner_step(w5);
    horner_step(w4);
    horner_step(w3);
    horner_step(w2);
    horner_step(w1);
    horner_step(w0);

    // out = (1 + w7)*x + A*z0 ; store with 16B vector stores
    {
        float to[4][8];
#pragma unroll
        for (int r = 0; r < 4; ++r)
#pragma unroll
            for (int j = 0; j < 8; ++j)
                to[r][j] = __shfl_xor(t[r][j], 1);
        const float wf = 1.0f + w7;
#pragma unroll
        for (int i = 0; i < 4; ++i) {
            float o[8];
#pragma unroll
            for (int j = 0; j < 8; ++j) {
                float s = wf * x[i][j];
#pragma unroll
                for (int r = 0; r < 4; ++r) s += A[i][r]     * t[r][j];
#pragma unroll
                for (int r = 0; r < 4; ++r) s += A[i][4 + r] * to[r][j];
                o[j] = s;
            }
            reinterpret_cast<float4*>(om)[2 * i]     = make_float4(o[0], o[1], o[2], o[3]);
            reinterpret_cast<float4*>(om)[2 * i + 1] = make_float4(o[4], o[5], o[6], o[7]);
        }
    }
}

extern "C" void kernel_launch(void* const* d_in, const int* in_sizes, int n_in,
                              void* d_out, int out_size, void* d_ws, size_t ws_size,
                              hipStream_t stream)
{
    const float* in = (const float*)d_in[0];
    const float* w  = (const float*)d_in[1];
    float* out      = (float*)d_out;

    const int nmat   = in_sizes[0] / 64;   // 2048*128 = 262144 matrices
    const int blocks = nmat / 128;         // 128 matrices per 256-thread block
    ns_poly_kernel<<<blocks, 256, 0, stream>>>(in, w, out);
}